// Round 5
// baseline (5288.625 us; speedup 1.0000x reference)
//
#include <hip/hip_runtime.h>

#define N_NODES  50000
#define N_EDGES  600000
#define DIM      128
#define N_LAYERS 5
#define N_GRAPHS 512
#define NB       ((N_NODES + 255) / 256)   // 196
#define ROWS_PER_BLOCK 196                 // 256 blocks * 196 = 50176 >= 50000

// ---------------------------------------------------------------- preprocess

// zero cnt, init graph ranges (replaces 3 memsets)
__global__ __launch_bounds__(256) void k_init(int* __restrict__ cnt,
                                              unsigned* __restrict__ gstart,
                                              unsigned* __restrict__ gend) {
    int i = blockIdx.x * 256 + threadIdx.x;
    if (i < N_NODES) cnt[i] = 0;
    if (i < N_GRAPHS) { gstart[i] = 0xFFFFFFFFu; gend[i] = 0u; }
}

// fused: in-degree count (edge-parallel) + graph ranges (node-parallel)
__global__ __launch_bounds__(256) void k_count_granges(const int* __restrict__ dst,
                                                       const int* __restrict__ batch,
                                                       int* __restrict__ cnt,
                                                       unsigned* __restrict__ gstart,
                                                       unsigned* __restrict__ gend) {
    int i = blockIdx.x * 256 + threadIdx.x;
    if (i < N_EDGES) atomicAdd(&cnt[dst[i]], 1);
    if (i < N_NODES) {
        int g = batch[i];
        atomicMin(&gstart[g], (unsigned)i);
        atomicMax(&gend[g],   (unsigned)(i + 1));
    }
}

__global__ __launch_bounds__(256) void k_bsum(const int* __restrict__ cnt,
                                              int* __restrict__ bsum) {
    __shared__ int ws[4];
    int i = blockIdx.x * 256 + threadIdx.x;
    int v = (i < N_NODES) ? cnt[i] : 0;
#pragma unroll
    for (int o = 32; o > 0; o >>= 1) v += __shfl_down(v, o, 64);
    if ((threadIdx.x & 63) == 0) ws[threadIdx.x >> 6] = v;
    __syncthreads();
    if (threadIdx.x == 0) bsum[blockIdx.x] = ws[0] + ws[1] + ws[2] + ws[3];
}

__global__ void k_scan_bsum(const int* __restrict__ bsum, int* __restrict__ boff) {
    __shared__ int s[256];
    int t = threadIdx.x;
    int v = (t < NB) ? bsum[t] : 0;
    s[t] = v;
    __syncthreads();
    for (int o = 1; o < 256; o <<= 1) {
        int u = (t >= o) ? s[t - o] : 0;
        __syncthreads();
        s[t] += u;
        __syncthreads();
    }
    if (t < NB) boff[t] = s[t] - v;
}

__global__ __launch_bounds__(256) void k_rowptr(const int* __restrict__ cnt,
                                                const int* __restrict__ boff,
                                                int* __restrict__ row_ptr,
                                                int* __restrict__ cursor,
                                                float* __restrict__ dinv) {
    __shared__ int s[256];
    int t = threadIdx.x;
    int i = blockIdx.x * 256 + t;
    int v = (i < N_NODES) ? cnt[i] : 0;
    s[t] = v;
    __syncthreads();
    for (int o = 1; o < 256; o <<= 1) {
        int u = (t >= o) ? s[t - o] : 0;
        __syncthreads();
        s[t] += u;
        __syncthreads();
    }
    int excl = boff[blockIdx.x] + s[t] - v;
    if (i < N_NODES) {
        row_ptr[i] = excl;
        cursor[i]  = excl;
        dinv[i]    = rsqrtf((float)(v + 1));
    } else if (i == N_NODES) {
        row_ptr[N_NODES] = excl;
    }
}

__global__ void k_fill(const int* __restrict__ src, const int* __restrict__ dst,
                       const float* __restrict__ dinv, int* __restrict__ cursor,
                       int* __restrict__ col, float* __restrict__ wnorm) {
    int e = blockIdx.x * blockDim.x + threadIdx.x;
    if (e < N_EDGES) {
        int d = dst[e], s = src[e];
        int pos = atomicAdd(&cursor[d], 1);
        col[pos]   = s;
        wnorm[pos] = dinv[s] * dinv[d];
    }
}

// ---------------------------------------------------------------- fused layer
// h_out = relu( (Ahat @ h_in) @ W + b ), one kernel per layer.
// 256 persistent blocks x 512 threads. Waves 0-3 (producer): gather 64-row
// agg tiles (half-wave per node, float4/lane, 8-deep unrolled gather) into
// double-buffered LDS. Waves 4-7 (consumer): GEMM from LDS (broadcast reads)
// with W fully LDS-resident, + bias + relu + store. GEMM's ~10.4us VALU floor
// hides under the ~40us L3-bound gather. All fp32, no float atomics.
__global__ __launch_bounds__(512, 1) void k_layer(const float* __restrict__ hin,
                                                  const float* __restrict__ W,
                                                  const float* __restrict__ bias,
                                                  float* __restrict__ hout,
                                                  const float* __restrict__ dinv,
                                                  const int* __restrict__ row_ptr,
                                                  const int* __restrict__ col,
                                                  const float* __restrict__ wnorm) {
    __shared__ float4 Wl[DIM * 32];      // [k][c4]  64 KB
    __shared__ float  At[2][64][DIM];    // 2 x 32 KB

    const int tid = threadIdx.x;
    const int rb0 = blockIdx.x * ROWS_PER_BLOCK;
    const int rb1 = (rb0 + ROWS_PER_BLOCK < N_NODES) ? rb0 + ROWS_PER_BLOCK : N_NODES;

    // stage W once (all 512 threads, coalesced)
    {
        const float4* Wg = (const float4*)W;
#pragma unroll
        for (int i = 0; i < 8; ++i) Wl[tid + i * 512] = Wg[tid + i * 512];
    }

    if (tid < 256) {
        // ---------------- producer: 4 gather waves ----------------
        const int w    = tid >> 6;
        const int half = (tid >> 5) & 1;
        const int slot = tid & 31;
        const float4* __restrict__ hin4 = (const float4*)hin + slot;

#define GATHER(CB, BUF)                                                       \
        {                                                                     \
            const int cb_ = (CB);                                             \
            _Pragma("unroll 1")                                               \
            for (int r = 0; r < 8; ++r) {                                     \
                int rl   = r * 8 + (w << 1) + half;                           \
                int node = cb_ + rl;                                          \
                if (node < rb1) {                                             \
                    float di = dinv[node];                                    \
                    float4 v = hin4[(size_t)node * 32];                       \
                    float4 a;                                                 \
                    a.x = v.x * di * di; a.y = v.y * di * di;                 \
                    a.z = v.z * di * di; a.w = v.w * di * di;                 \
                    int e0 = row_ptr[node], e1 = row_ptr[node + 1];           \
                    int last = e1 - 1;                                        \
                    for (int e = e0; e < e1; e += 8) {                        \
                        int jj[8]; float wt[8];                               \
                        _Pragma("unroll")                                     \
                        for (int i = 0; i < 8; ++i) {                         \
                            int ee = e + i;                                   \
                            int cl = (ee <= last) ? ee : last;                \
                            jj[i] = col[cl];                                  \
                            wt[i] = (ee <= last) ? wnorm[cl] : 0.f;           \
                        }                                                     \
                        float4 u[8];                                          \
                        _Pragma("unroll")                                     \
                        for (int i = 0; i < 8; ++i)                           \
                            u[i] = hin4[(size_t)jj[i] * 32];                  \
                        _Pragma("unroll")                                     \
                        for (int i = 0; i < 8; ++i) {                         \
                            a.x += u[i].x * wt[i]; a.y += u[i].y * wt[i];     \
                            a.z += u[i].z * wt[i]; a.w += u[i].w * wt[i];     \
                        }                                                     \
                    }                                                         \
                    ((float4*)&At[BUF][rl][0])[slot] = a;                     \
                }                                                             \
            }                                                                 \
        }

        GATHER(rb0, 0)                      // prologue: chunk 0 -> buf 0
        __syncthreads();
#pragma unroll 1
        for (int c = 0; c < 4; ++c) {
            int cb = rb0 + (c + 1) * 64;
            if (c < 3 && cb < rb1) GATHER(cb, (c + 1) & 1)
            __syncthreads();
        }
#undef GATHER
    } else {
        // ---------------- consumer: 4 GEMM waves ----------------
        const int g  = tid - 256;
        const int tc = g & 31;               // col group: cols tc*4..tc*4+3
        const int tr = g >> 5;               // row group: rows tr*8..tr*8+7
        const float4 bv = ((const float4*)bias)[tc];

        __syncthreads();                     // matches producer prologue barrier
#pragma unroll 1
        for (int c = 0; c < 4; ++c) {
            int cb = rb0 + c * 64;
            if (cb < rb1) {
                const int b = c & 1;
                float acc[8][4] = {};
#pragma unroll
                for (int k4 = 0; k4 < 32; ++k4) {
                    float4 w0 = Wl[(k4 * 4 + 0) * 32 + tc];
                    float4 w1 = Wl[(k4 * 4 + 1) * 32 + tc];
                    float4 w2 = Wl[(k4 * 4 + 2) * 32 + tc];
                    float4 w3 = Wl[(k4 * 4 + 3) * 32 + tc];
#pragma unroll
                    for (int rr = 0; rr < 8; ++rr) {
                        float4 a = *(const float4*)&At[b][tr * 8 + rr][k4 * 4];
                        acc[rr][0] += a.x * w0.x + a.y * w1.x + a.z * w2.x + a.w * w3.x;
                        acc[rr][1] += a.x * w0.y + a.y * w1.y + a.z * w2.y + a.w * w3.y;
                        acc[rr][2] += a.x * w0.z + a.y * w1.z + a.z * w2.z + a.w * w3.z;
                        acc[rr][3] += a.x * w0.w + a.y * w1.w + a.z * w2.w + a.w * w3.w;
                    }
                }
#pragma unroll
                for (int rr = 0; rr < 8; ++rr) {
                    int node = cb + tr * 8 + rr;
                    if (node < rb1) {
                        float4 o;
                        o.x = fmaxf(acc[rr][0] + bv.x, 0.f);
                        o.y = fmaxf(acc[rr][1] + bv.y, 0.f);
                        o.z = fmaxf(acc[rr][2] + bv.z, 0.f);
                        o.w = fmaxf(acc[rr][3] + bv.w, 0.f);
                        ((float4*)hout)[(size_t)node * 32 + tc] = o;
                    }
                }
            }
            __syncthreads();
        }
    }
}

// ---------------------------------------------------------------- pooling
__global__ __launch_bounds__(512) void k_pool(const float* __restrict__ h,
                                              const unsigned* __restrict__ gstart,
                                              const unsigned* __restrict__ gend,
                                              float* __restrict__ out, int layer) {
    __shared__ float4 red[16][32];
    int g    = blockIdx.x;
    int slot = threadIdx.x & 31;
    int way  = threadIdx.x >> 5;
    unsigned s = gstart[g], e = gend[g];
    float4 sum = make_float4(0.f, 0.f, 0.f, 0.f);
    if (s != 0xFFFFFFFFu) {
        for (unsigned i = s + way; i < e; i += 16) {
            float4 v = *(const float4*)&h[(size_t)i * DIM + slot * 4];
            sum.x += v.x; sum.y += v.y; sum.z += v.z; sum.w += v.w;
        }
    }
    red[way][slot] = sum;
    __syncthreads();
    if (threadIdx.x < 32) {
        float4 t = red[0][slot];
#pragma unroll
        for (int wy = 1; wy < 16; ++wy) {
            float4 v = red[wy][slot];
            t.x += v.x; t.y += v.y; t.z += v.z; t.w += v.w;
        }
        *(float4*)&out[(size_t)g * (N_LAYERS * DIM) + layer * DIM + slot * 4] = t;
    }
}

// ---------------------------------------------------------------- launch

extern "C" void kernel_launch(void* const* d_in, const int* in_sizes, int n_in,
                              void* d_out, int out_size, void* d_ws, size_t ws_size,
                              hipStream_t stream) {
    const float* x    = (const float*)d_in[0];
    const int*   ei   = (const int*)d_in[1];
    const int*   bat  = (const int*)d_in[2];
    const float* Ws   = (const float*)d_in[3];
    const float* bs   = (const float*)d_in[4];
    float*       outp = (float*)d_out;

    const int* srcp = ei;
    const int* dstp = ei + N_EDGES;

    char* base = (char*)d_ws;
    size_t off = 0;
    float*    hP      = (float*)(base + off); off += (size_t)N_NODES * DIM * 4;
    float*    hQ      = (float*)(base + off); off += (size_t)N_NODES * DIM * 4;
    float*    dinv    = (float*)(base + off); off += (size_t)N_NODES * 4;
    int*      cnt     = (int*)(base + off);   off += (size_t)N_NODES * 4;
    int*      row_ptr = (int*)(base + off);   off += 200016;
    int*      cursor  = (int*)(base + off);   off += (size_t)N_NODES * 4;
    int*      col     = (int*)(base + off);   off += (size_t)N_EDGES * 4;
    float*    wnorm   = (float*)(base + off); off += (size_t)N_EDGES * 4;
    int*      bsum    = (int*)(base + off);   off += 1024;
    int*      boff    = (int*)(base + off);   off += 1024;
    unsigned* gstart  = (unsigned*)(base + off); off += 2048;
    unsigned* gend    = (unsigned*)(base + off); off += 2048;

    const int BE = (N_EDGES + 255) / 256;   // 2344

    k_init<<<NB, 256, 0, stream>>>(cnt, gstart, gend);
    k_count_granges<<<BE, 256, 0, stream>>>(dstp, bat, cnt, gstart, gend);
    k_bsum<<<NB, 256, 0, stream>>>(cnt, bsum);
    k_scan_bsum<<<1, 256, 0, stream>>>(bsum, boff);
    k_rowptr<<<NB, 256, 0, stream>>>(cnt, boff, row_ptr, cursor, dinv);
    k_fill<<<BE, 256, 0, stream>>>(srcp, dstp, dinv, cursor, col, wnorm);

    const float* hin = x;
    float* houts[N_LAYERS] = { hP, hQ, hP, hQ, hP };
    for (int l = 0; l < N_LAYERS; ++l) {
        float* ho = houts[l];
        k_layer<<<256, 512, 0, stream>>>(hin, Ws + (size_t)l * DIM * DIM,
                                         bs + (size_t)l * DIM, ho,
                                         dinv, row_ptr, col, wnorm);
        k_pool<<<N_GRAPHS, 512, 0, stream>>>(ho, gstart, gend, outp, l);
        hin = ho;
    }
}

// Round 6
// 471.645 us; speedup vs baseline: 11.2131x; 11.2131x over previous
//
#include <hip/hip_runtime.h>

#define N_NODES  50000
#define N_EDGES  600000
#define DIM      128
#define N_LAYERS 5
#define N_GRAPHS 512
#define NB       ((N_NODES + 255) / 256)   // 196

// bf16 <-> f32 bit helpers (RNE)
__device__ __forceinline__ unsigned short f2b(float f) {
    unsigned u = __float_as_uint(f);
    return (unsigned short)((u + 0x7FFFu + ((u >> 16) & 1u)) >> 16);
}
__device__ __forceinline__ float4 b2f4(ushort4 u) {
    float4 c;
    c.x = __uint_as_float((unsigned)u.x << 16);
    c.y = __uint_as_float((unsigned)u.y << 16);
    c.z = __uint_as_float((unsigned)u.z << 16);
    c.w = __uint_as_float((unsigned)u.w << 16);
    return c;
}

// ---------------------------------------------------------------- preprocess

__global__ __launch_bounds__(256) void k_init(int* __restrict__ cnt,
                                              unsigned* __restrict__ gstart,
                                              unsigned* __restrict__ gend) {
    int i = blockIdx.x * 256 + threadIdx.x;
    if (i < N_NODES) cnt[i] = 0;
    if (i < N_GRAPHS) { gstart[i] = 0xFFFFFFFFu; gend[i] = 0u; }
}

__global__ __launch_bounds__(256) void k_count_granges(const int* __restrict__ dst,
                                                       const int* __restrict__ batch,
                                                       int* __restrict__ cnt,
                                                       unsigned* __restrict__ gstart,
                                                       unsigned* __restrict__ gend) {
    int i = blockIdx.x * 256 + threadIdx.x;
    if (i < N_EDGES) atomicAdd(&cnt[dst[i]], 1);
    if (i < N_NODES) {
        int g = batch[i];
        atomicMin(&gstart[g], (unsigned)i);
        atomicMax(&gend[g],   (unsigned)(i + 1));
    }
}

__global__ __launch_bounds__(256) void k_bsum(const int* __restrict__ cnt,
                                              int* __restrict__ bsum) {
    __shared__ int ws[4];
    int i = blockIdx.x * 256 + threadIdx.x;
    int v = (i < N_NODES) ? cnt[i] : 0;
#pragma unroll
    for (int o = 32; o > 0; o >>= 1) v += __shfl_down(v, o, 64);
    if ((threadIdx.x & 63) == 0) ws[threadIdx.x >> 6] = v;
    __syncthreads();
    if (threadIdx.x == 0) bsum[blockIdx.x] = ws[0] + ws[1] + ws[2] + ws[3];
}

__global__ void k_scan_bsum(const int* __restrict__ bsum, int* __restrict__ boff) {
    __shared__ int s[256];
    int t = threadIdx.x;
    int v = (t < NB) ? bsum[t] : 0;
    s[t] = v;
    __syncthreads();
    for (int o = 1; o < 256; o <<= 1) {
        int u = (t >= o) ? s[t - o] : 0;
        __syncthreads();
        s[t] += u;
        __syncthreads();
    }
    if (t < NB) boff[t] = s[t] - v;
}

__global__ __launch_bounds__(256) void k_rowptr(const int* __restrict__ cnt,
                                                const int* __restrict__ boff,
                                                int* __restrict__ row_ptr,
                                                int* __restrict__ cursor,
                                                float* __restrict__ dinv) {
    __shared__ int s[256];
    int t = threadIdx.x;
    int i = blockIdx.x * 256 + t;
    int v = (i < N_NODES) ? cnt[i] : 0;
    s[t] = v;
    __syncthreads();
    for (int o = 1; o < 256; o <<= 1) {
        int u = (t >= o) ? s[t - o] : 0;
        __syncthreads();
        s[t] += u;
        __syncthreads();
    }
    int excl = boff[blockIdx.x] + s[t] - v;
    if (i < N_NODES) {
        row_ptr[i] = excl;
        cursor[i]  = excl;
        dinv[i]    = rsqrtf((float)(v + 1));
    } else if (i == N_NODES) {
        row_ptr[N_NODES] = excl;
    }
}

__global__ void k_fill(const int* __restrict__ src, const int* __restrict__ dst,
                       const float* __restrict__ dinv, int* __restrict__ cursor,
                       int* __restrict__ col, float* __restrict__ wnorm) {
    int e = blockIdx.x * blockDim.x + threadIdx.x;
    if (e < N_EDGES) {
        int d = dst[e], s = src[e];
        int pos = atomicAdd(&cursor[d], 1);
        col[pos]   = s;
        wnorm[pos] = dinv[s] * dinv[d];
    }
}

// x (f32) -> xb (bf16), vectorized grid-stride
__global__ __launch_bounds__(256) void k_cvt(const float* __restrict__ x,
                                             unsigned short* __restrict__ xb) {
    const int total = N_NODES * 32;    // float4 groups
    for (int t = blockIdx.x * 256 + threadIdx.x; t < total; t += gridDim.x * 256) {
        float4 v = ((const float4*)x)[t];
        ushort4 o;
        o.x = f2b(v.x); o.y = f2b(v.y); o.z = f2b(v.z); o.w = f2b(v.w);
        ((ushort4*)xb)[t] = o;
    }
}

// ---------------------------------------------------------------- aggregation
// bf16 input rows (256B), fp32 accumulate, fp32 output. Half-wave per node:
// 2 nodes/wave, ushort4 (8B)/lane. 8-deep unrolled gather (16 loads in
// flight/wave); OOB slots clamp to the row's last edge, weight 0.
__global__ __launch_bounds__(256) void k_agg_b(const unsigned short* __restrict__ hin,
                                               float* __restrict__ agg,
                                               const float* __restrict__ dinv,
                                               const int* __restrict__ row_ptr,
                                               const int* __restrict__ col,
                                               const float* __restrict__ wnorm) {
    const int wid  = blockIdx.x * 4 + (threadIdx.x >> 6);
    const int half = (threadIdx.x >> 5) & 1;
    const int node = wid * 2 + half;            // 6250*4*2 = 50000 exactly
    const int slot = threadIdx.x & 31;
    const ushort4* __restrict__ hin4 = (const ushort4*)hin + slot;

    float di = dinv[node];
    float4 v = b2f4(hin4[(size_t)node * 32]);
    float4 acc;
    acc.x = v.x * di * di; acc.y = v.y * di * di;   // self-loop
    acc.z = v.z * di * di; acc.w = v.w * di * di;

    int e0 = row_ptr[node], e1 = row_ptr[node + 1];
    const int last = e1 - 1;
    for (int e = e0; e < e1; e += 8) {
        int jj[8]; float wt[8];
#pragma unroll
        for (int i = 0; i < 8; ++i) {
            int ee = e + i;
            int cl = (ee <= last) ? ee : last;
            jj[i] = col[cl];
            wt[i] = (ee <= last) ? wnorm[cl] : 0.f;
        }
        ushort4 u[8];
#pragma unroll
        for (int i = 0; i < 8; ++i) u[i] = hin4[(size_t)jj[i] * 32];
#pragma unroll
        for (int i = 0; i < 8; ++i) {
            float4 f = b2f4(u[i]);
            acc.x += f.x * wt[i]; acc.y += f.y * wt[i];
            acc.z += f.z * wt[i]; acc.w += f.w * wt[i];
        }
    }
    ((float4*)agg)[(size_t)node * 32 + slot] = acc;
}

// ---------------------------------------------------------------- GEMM + bias + relu
// out(bf16) = relu(A(f32) @ W + b). Full W in LDS (64KB). 64-row tile, 256
// threads, 8 rows x 4 cols/thread. A read from global with row-group broadcast
// (L1-resident), double-buffered in named reg arrays (static idx only).
__global__ __launch_bounds__(256, 2) void k_gemm(const float* __restrict__ A,
                                                 const float* __restrict__ W,
                                                 const float* __restrict__ bias,
                                                 unsigned short* __restrict__ out) {
    __shared__ float4 Wl[DIM * 32];     // [k][c4], 65536 B

    const int tid = threadIdx.x;
    const int tc  = tid & 31;
    const int tr  = tid >> 5;
    const int rb  = blockIdx.x * 64;

    const float4* Wg = (const float4*)W;
#pragma unroll
    for (int i = 0; i < 16; ++i) Wl[tid + i * 256] = Wg[tid + i * 256];
    __syncthreads();

    const float4* ap[8];
#pragma unroll
    for (int r = 0; r < 8; ++r) {
        int crow = rb + tr * 8 + r;
        if (crow > N_NODES - 1) crow = N_NODES - 1;   // clamp loads; store guarded
        ap[r] = (const float4*)A + (size_t)crow * 32;
    }

    float acc[8][4] = {};
    float4 a0[8], a1[8];
#pragma unroll
    for (int r = 0; r < 8; ++r) a0[r] = ap[r][0];

#define GEMM_STEP(AF, PF, K4)                                             \
    {                                                                     \
        _Pragma("unroll")                                                 \
        for (int r = 0; r < 8; ++r) PF[r] = ap[r][(K4) + 1];              \
        float4 w0 = Wl[((K4) * 4 + 0) * 32 + tc];                         \
        float4 w1 = Wl[((K4) * 4 + 1) * 32 + tc];                         \
        float4 w2 = Wl[((K4) * 4 + 2) * 32 + tc];                         \
        float4 w3 = Wl[((K4) * 4 + 3) * 32 + tc];                         \
        _Pragma("unroll")                                                 \
        for (int r = 0; r < 8; ++r) {                                     \
            acc[r][0] += AF[r].x * w0.x; acc[r][1] += AF[r].x * w0.y;     \
            acc[r][2] += AF[r].x * w0.z; acc[r][3] += AF[r].x * w0.w;     \
            acc[r][0] += AF[r].y * w1.x; acc[r][1] += AF[r].y * w1.y;     \
            acc[r][2] += AF[r].y * w1.z; acc[r][3] += AF[r].y * w1.w;     \
            acc[r][0] += AF[r].z * w2.x; acc[r][1] += AF[r].z * w2.y;     \
            acc[r][2] += AF[r].z * w2.z; acc[r][3] += AF[r].z * w2.w;     \
            acc[r][0] += AF[r].w * w3.x; acc[r][1] += AF[r].w * w3.y;     \
            acc[r][2] += AF[r].w * w3.z; acc[r][3] += AF[r].w * w3.w;     \
        }                                                                 \
    }

    // final prefetch reads 16B past row 49999 -> stays inside d_ws: safe.
    for (int k8 = 0; k8 < 16; ++k8) {
        GEMM_STEP(a0, a1, 2 * k8)
        GEMM_STEP(a1, a0, 2 * k8 + 1)
    }
#undef GEMM_STEP

    float4 bv = ((const float4*)bias)[tc];
#pragma unroll
    for (int r = 0; r < 8; ++r) {
        int grow = rb + tr * 8 + r;
        if (grow < N_NODES) {
            ushort4 o;
            o.x = f2b(fmaxf(acc[r][0] + bv.x, 0.f));
            o.y = f2b(fmaxf(acc[r][1] + bv.y, 0.f));
            o.z = f2b(fmaxf(acc[r][2] + bv.z, 0.f));
            o.w = f2b(fmaxf(acc[r][3] + bv.w, 0.f));
            ((ushort4*)out)[(size_t)grow * 32 + tc] = o;
        }
    }
}

// ---------------------------------------------------------------- pooling (bf16 in)
__global__ __launch_bounds__(512) void k_pool_b(const unsigned short* __restrict__ h,
                                                const unsigned* __restrict__ gstart,
                                                const unsigned* __restrict__ gend,
                                                float* __restrict__ out, int layer) {
    __shared__ float4 red[16][32];
    int g    = blockIdx.x;
    int slot = threadIdx.x & 31;
    int way  = threadIdx.x >> 5;
    unsigned s = gstart[g], e = gend[g];
    float4 sum = make_float4(0.f, 0.f, 0.f, 0.f);
    if (s != 0xFFFFFFFFu) {
        for (unsigned i = s + way; i < e; i += 16) {
            float4 v = b2f4(((const ushort4*)h)[(size_t)i * 32 + slot]);
            sum.x += v.x; sum.y += v.y; sum.z += v.z; sum.w += v.w;
        }
    }
    red[way][slot] = sum;
    __syncthreads();
    if (threadIdx.x < 32) {
        float4 t = red[0][slot];
#pragma unroll
        for (int wy = 1; wy < 16; ++wy) {
            float4 v = red[wy][slot];
            t.x += v.x; t.y += v.y; t.z += v.z; t.w += v.w;
        }
        *(float4*)&out[(size_t)g * (N_LAYERS * DIM) + layer * DIM + slot * 4] = t;
    }
}

// ---------------------------------------------------------------- launch

extern "C" void kernel_launch(void* const* d_in, const int* in_sizes, int n_in,
                              void* d_out, int out_size, void* d_ws, size_t ws_size,
                              hipStream_t stream) {
    const float* x    = (const float*)d_in[0];
    const int*   ei   = (const int*)d_in[1];
    const int*   bat  = (const int*)d_in[2];
    const float* Ws   = (const float*)d_in[3];
    const float* bs   = (const float*)d_in[4];
    float*       outp = (float*)d_out;

    const int* srcp = ei;
    const int* dstp = ei + N_EDGES;

    char* base = (char*)d_ws;
    size_t off = 0;
    float*          hP      = (float*)(base + off);          off += (size_t)N_NODES * DIM * 4;  // agg out, f32
    unsigned short* xb      = (unsigned short*)(base + off); off += (size_t)N_NODES * DIM * 2;
    unsigned short* hB0     = (unsigned short*)(base + off); off += (size_t)N_NODES * DIM * 2;
    unsigned short* hB1     = (unsigned short*)(base + off); off += (size_t)N_NODES * DIM * 2;
    float*          dinv    = (float*)(base + off);          off += (size_t)N_NODES * 4;
    int*            cnt     = (int*)(base + off);            off += (size_t)N_NODES * 4;
    int*            row_ptr = (int*)(base + off);            off += 200016;
    int*            cursor  = (int*)(base + off);            off += (size_t)N_NODES * 4;
    int*            col     = (int*)(base + off);            off += (size_t)N_EDGES * 4;
    float*          wnorm   = (float*)(base + off);          off += (size_t)N_EDGES * 4;
    int*            bsum    = (int*)(base + off);            off += 1024;
    int*            boff    = (int*)(base + off);            off += 1024;
    unsigned*       gstart  = (unsigned*)(base + off);       off += 2048;
    unsigned*       gend    = (unsigned*)(base + off);       off += 2048;

    const int BE = (N_EDGES + 255) / 256;   // 2344

    k_cvt<<<2048, 256, 0, stream>>>(x, xb);
    k_init<<<NB, 256, 0, stream>>>(cnt, gstart, gend);
    k_count_granges<<<BE, 256, 0, stream>>>(dstp, bat, cnt, gstart, gend);
    k_bsum<<<NB, 256, 0, stream>>>(cnt, bsum);
    k_scan_bsum<<<1, 256, 0, stream>>>(bsum, boff);
    k_rowptr<<<NB, 256, 0, stream>>>(cnt, boff, row_ptr, cursor, dinv);
    k_fill<<<BE, 256, 0, stream>>>(srcp, dstp, dinv, cursor, col, wnorm);

    const int BAGG  = 6250;                   // 6250 * 4 waves * 2 nodes = 50000
    const int BGEMM = (N_NODES + 63) / 64;    // 782

    const unsigned short* hin = xb;
    unsigned short* houts[N_LAYERS] = { hB0, hB1, hB0, hB1, hB0 };
    for (int l = 0; l < N_LAYERS; ++l) {
        unsigned short* ho = houts[l];
        k_agg_b<<<BAGG, 256, 0, stream>>>(hin, hP, dinv, row_ptr, col, wnorm);
        k_gemm<<<BGEMM, 256, 0, stream>>>(hP, Ws + (size_t)l * DIM * DIM,
                                          bs + (size_t)l * DIM, ho);
        k_pool_b<<<N_GRAPHS, 512, 0, stream>>>(ho, gstart, gend, outp, l);
        hin = ho;
    }
}